// Round 5
// baseline (249.756 us; speedup 1.0000x reference)
//
#include <hip/hip_runtime.h>
#include <math.h>

#define N_ROWS 131072
#define DIM 64
#define KCODES 512

// float-element offsets into d_out (concatenated outputs, all read back as f32)
#define O_LOSS 0
#define O_Q    1ull
#define O_PERP 8388609ull
#define O_ENC  8388610ull
#define O_IDX  75497474ull

// ambiguity window: rigorous |approx - exact| bound is <5e-5; 8x safety.
#define AMB_WIN 4.0e-4f
#define AMB_CAP 16384

using sh8   = __attribute__((ext_vector_type(8))) short;
using f32x4 = __attribute__((ext_vector_type(4))) float;

// round-to-nearest-even bf16 of f32, returned as the f32 bit pattern pre-shift
__device__ __forceinline__ unsigned bf16rne_bits(float x) {
    unsigned u = __float_as_uint(x);
    return u + 0x7fffu + ((u >> 16) & 1u);
}

// swizzled ushort index into a [rows][64] bf16 LDS tile (16B-granule XOR on rows)
__device__ __forceinline__ int bswz(int r, int k) {
    return r * 64 + (k ^ ((r & 7) << 3));
}

// ---------------- K1 prep: exact ||e||^2 (numpy 8-acc pairwise), zero accumulators ----------------
__global__ void vq_prep(const float* __restrict__ emb, float* __restrict__ bsq,
                        int* __restrict__ counts, double* __restrict__ loss_acc,
                        int* __restrict__ amb_count) {
#pragma clang fp contract(off)
    int c = blockIdx.x * blockDim.x + threadIdx.x;
    if (c < KCODES) {
        const float* e = emb + (size_t)c * DIM;
        float r[8];
#pragma unroll
        for (int j = 0; j < 8; ++j) { float v = e[j]; r[j] = v * v; }
#pragma unroll
        for (int i = 8; i < 64; i += 8)
#pragma unroll
            for (int j = 0; j < 8; ++j) { float v = e[i + j]; r[j] = r[j] + v * v; }
        bsq[c] = ((r[0] + r[1]) + (r[2] + r[3])) + ((r[4] + r[5]) + (r[6] + r[7]));
        counts[c] = 0;
    }
    if (blockIdx.x == 0 && threadIdx.x == 0) { *loss_acc = 0.0; *amb_count = 0; }
}

// ---------------- K2: MFMA bf16x3 distances + provisional argmin + enc/Q/loss ----------------
__global__ __launch_bounds__(256, 3) void vq_mfma(
    const float* __restrict__ x, const float* __restrict__ emb,
    const float* __restrict__ bsq, int* __restrict__ counts,
    double* __restrict__ loss_acc, float* __restrict__ out,
    int* __restrict__ amb_count, int* __restrict__ amb_rows)
{
    __shared__ __align__(16) unsigned short Xh[64 * 64];
    __shared__ __align__(16) unsigned short Xl[64 * 64];
    __shared__ __align__(16) unsigned short Eh[128 * 64];
    __shared__ __align__(16) unsigned short El[128 * 64];
    __shared__ float  bsql[KCODES];
    __shared__ int    idx_l[64];
    __shared__ double wsum[4];

    const int tid  = threadIdx.x;
    const int row0 = blockIdx.x * 64;
    const int l    = tid & 63;     // lane
    const int w    = tid >> 6;     // wave 0..3

    // ---- stage X as bf16 hi/lo (swizzled) ----
#pragma unroll
    for (int k = 0; k < 4; ++k) {
        int i = tid + k * 256;               // 0..1023 float4-units
        int r = i >> 4, c4 = i & 15;
        float4 v = *reinterpret_cast<const float4*>(&x[(size_t)(row0 + r) * 64 + c4 * 4]);
        unsigned t0 = bf16rne_bits(v.x), t1 = bf16rne_bits(v.y);
        unsigned t2 = bf16rne_bits(v.z), t3 = bf16rne_bits(v.w);
        float r0 = v.x - __uint_as_float(t0 & 0xffff0000u);
        float r1 = v.y - __uint_as_float(t1 & 0xffff0000u);
        float r2 = v.z - __uint_as_float(t2 & 0xffff0000u);
        float r3 = v.w - __uint_as_float(t3 & 0xffff0000u);
        unsigned s0 = bf16rne_bits(r0), s1 = bf16rne_bits(r1);
        unsigned s2 = bf16rne_bits(r2), s3 = bf16rne_bits(r3);
        int ua = bswz(r, c4 * 4);            // %4 == 0, XOR touches bits 3..5 only
        *reinterpret_cast<uint2*>(&Xh[ua]) = make_uint2((t0 >> 16) | (t1 & 0xffff0000u),
                                                        (t2 >> 16) | (t3 & 0xffff0000u));
        *reinterpret_cast<uint2*>(&Xl[ua]) = make_uint2((s0 >> 16) | (s1 & 0xffff0000u),
                                                        (s2 >> 16) | (s3 & 0xffff0000u));
    }
    // bsq -> LDS
#pragma unroll
    for (int k = 0; k < 2; ++k) bsql[tid + k * 256] = bsq[tid + k * 256];

    float m1[4], m2[4];
    int   i1[4];
#pragma unroll
    for (int j = 0; j < 4; ++j) { m1[j] = 3.4e38f; m2[j] = 3.4e38f; i1[j] = 0; }

    const int arow = w * 16 + (l & 15);      // A-fragment row for this lane
    const int ka   = (l >> 4) * 8;           // k-offset for this lane

    for (int ch = 0; ch < 4; ++ch) {
        // ---- stage E chunk (128 codes) as bf16 hi/lo ----
        if (ch > 0) __syncthreads();         // everyone done reading previous chunk
#pragma unroll
        for (int k = 0; k < 8; ++k) {
            int i = tid + k * 256;           // 0..2047 float4-units
            int c = i >> 4, c4 = i & 15;
            float4 v = *reinterpret_cast<const float4*>(&emb[(size_t)(ch * 128 + c) * 64 + c4 * 4]);
            unsigned t0 = bf16rne_bits(v.x), t1 = bf16rne_bits(v.y);
            unsigned t2 = bf16rne_bits(v.z), t3 = bf16rne_bits(v.w);
            float r0 = v.x - __uint_as_float(t0 & 0xffff0000u);
            float r1 = v.y - __uint_as_float(t1 & 0xffff0000u);
            float r2 = v.z - __uint_as_float(t2 & 0xffff0000u);
            float r3 = v.w - __uint_as_float(t3 & 0xffff0000u);
            unsigned s0 = bf16rne_bits(r0), s1 = bf16rne_bits(r1);
            unsigned s2 = bf16rne_bits(r2), s3 = bf16rne_bits(r3);
            int ua = bswz(c, c4 * 4);
            *reinterpret_cast<uint2*>(&Eh[ua]) = make_uint2((t0 >> 16) | (t1 & 0xffff0000u),
                                                            (t2 >> 16) | (t3 & 0xffff0000u));
            *reinterpret_cast<uint2*>(&El[ua]) = make_uint2((s0 >> 16) | (s1 & 0xffff0000u),
                                                            (s2 >> 16) | (s3 & 0xffff0000u));
        }
        __syncthreads();

        // A-fragments for this wave (reused across 8 col-tiles)
        sh8 ah0 = *reinterpret_cast<const sh8*>(&Xh[bswz(arow, ka)]);
        sh8 ah1 = *reinterpret_cast<const sh8*>(&Xh[bswz(arow, ka + 32)]);
        sh8 al0 = *reinterpret_cast<const sh8*>(&Xl[bswz(arow, ka)]);
        sh8 al1 = *reinterpret_cast<const sh8*>(&Xl[bswz(arow, ka + 32)]);

#pragma unroll
        for (int ct = 0; ct < 8; ++ct) {
            int bc = ct * 16 + (l & 15);     // code within chunk
            sh8 bh0 = *reinterpret_cast<const sh8*>(&Eh[bswz(bc, ka)]);
            sh8 bh1 = *reinterpret_cast<const sh8*>(&Eh[bswz(bc, ka + 32)]);
            sh8 bl0 = *reinterpret_cast<const sh8*>(&El[bswz(bc, ka)]);
            sh8 bl1 = *reinterpret_cast<const sh8*>(&El[bswz(bc, ka + 32)]);
            f32x4 acc = {0.f, 0.f, 0.f, 0.f};
            acc = __builtin_amdgcn_mfma_f32_16x16x32_bf16(ah0, bh0, acc, 0, 0, 0);
            acc = __builtin_amdgcn_mfma_f32_16x16x32_bf16(ah1, bh1, acc, 0, 0, 0);
            acc = __builtin_amdgcn_mfma_f32_16x16x32_bf16(ah0, bl0, acc, 0, 0, 0);
            acc = __builtin_amdgcn_mfma_f32_16x16x32_bf16(ah1, bl1, acc, 0, 0, 0);
            acc = __builtin_amdgcn_mfma_f32_16x16x32_bf16(al0, bh0, acc, 0, 0, 0);
            acc = __builtin_amdgcn_mfma_f32_16x16x32_bf16(al1, bh1, acc, 0, 0, 0);

            int code = ch * 128 + bc;
            float bs = bsql[code];
#pragma unroll
            for (int j = 0; j < 4; ++j) {
                float tt = bs - 2.0f * acc[j];   // sx dropped: uniform per-row shift
                if (tt < m1[j]) { m2[j] = m1[j]; m1[j] = tt; i1[j] = code; }
                else if (tt < m2[j]) { m2[j] = tt; }
            }
        }
    }

    // ---- reduce (min, argmin, 2nd-min) across the 16 lanes sharing (l>>4) ----
#pragma unroll
    for (int off = 8; off >= 1; off >>= 1)
#pragma unroll
        for (int j = 0; j < 4; ++j) {
            float ov1 = __shfl_xor(m1[j], off, 64);
            int   oi1 = __shfl_xor(i1[j], off, 64);
            float ov2 = __shfl_xor(m2[j], off, 64);
            float hi  = fmaxf(m1[j], ov1);
            m2[j] = fminf(fminf(m2[j], ov2), hi);
            if (ov1 < m1[j] || (ov1 == m1[j] && oi1 < i1[j])) { m1[j] = ov1; i1[j] = oi1; }
        }

    if ((l & 15) == 0) {
#pragma unroll
        for (int j = 0; j < 4; ++j) {
            int r_loc = w * 16 + ((l >> 4) << 2) + j;   // D row = (lane>>4)*4 + reg
            idx_l[r_loc] = i1[j];
            out[O_IDX + row0 + r_loc] = (float)i1[j];
            atomicAdd(&counts[i1[j]], 1);
            if (m2[j] - m1[j] <= AMB_WIN) {
                int slot = atomicAdd(amb_count, 1);
                if (slot < AMB_CAP) amb_rows[slot] = row0 + r_loc;
            }
        }
    }
    __syncthreads();

    // ---- quantized_st + loss partial (x re-read: L3-hot, same block) ----
    double lsum = 0.0;
#pragma unroll 4
    for (int k = 0; k < 16; ++k) {
        int i = tid + k * 256;               // 0..4095
        int r = i >> 6, d = i & 63;
        int id = idx_l[r];
        float xv = x[(size_t)(row0 + r) * 64 + d];
        float ev = emb[(size_t)id * 64 + d];
        float diff = ev - xv;
        out[O_Q + (size_t)(row0 + r) * 64 + d] = xv + diff;
        lsum += (double)diff * (double)diff;
    }

    // ---- one-hot encodings (64 rows x 512) as float2 ----
    float2* enc2 = reinterpret_cast<float2*>(out + O_ENC + (size_t)row0 * KCODES);
#pragma unroll 4
    for (int k = 0; k < 64; ++k) {
        int i = tid + k * 256;               // 0..16383 float2s
        int r = i >> 8;
        int c = (i & 255) * 2;
        int id = idx_l[r];
        float2 v;
        v.x = (c     == id) ? 1.f : 0.f;
        v.y = (c + 1 == id) ? 1.f : 0.f;
        enc2[i] = v;
    }

#pragma unroll
    for (int off = 32; off >= 1; off >>= 1) lsum += __shfl_xor(lsum, off, 64);
    if ((tid & 63) == 0) wsum[tid >> 6] = lsum;
    __syncthreads();
    if (tid == 0) atomicAdd(loss_acc, wsum[0] + wsum[1] + wsum[2] + wsum[3]);
}

// ---------------- K3: bit-exact np-replica recompute for ambiguous rows ----------------
__global__ __launch_bounds__(256, 2) void vq_fixup(
    const float* __restrict__ x, const float* __restrict__ emb,
    const float* __restrict__ bsq, int* __restrict__ counts,
    double* __restrict__ loss_acc, float* __restrict__ out,
    const int* __restrict__ amb_count, const int* __restrict__ amb_rows)
{
#pragma clang fp contract(off)
    __shared__ float Xt[64 * 34];     // Xt[d*34 + r], 32 rows
    __shared__ float Et[64 * 68];     // Et[d*68 + c], 64 codes/chunk
    __shared__ float sx_l[32];
    __shared__ int   rowid_l[32];

    const int tid = threadIdx.x;
    const int tx  = tid & 15;         // 4 codes each
    const int ty  = tid >> 4;         // 2 rows each
    int n = *amb_count; if (n > AMB_CAP) n = AMB_CAP;

    for (int base = blockIdx.x * 32; base < n; base += gridDim.x * 32) {
        const int nrows = min(32, n - base);
        if (tid < 32) {
            int e = base + tid;
            rowid_l[tid] = amb_rows[e < n ? e : (n - 1)];
        }
        __syncthreads();

        // stage X rows transposed
#pragma unroll
        for (int k = 0; k < 8; ++k) {
            int i = tid + k * 256;    // 0..2047
            int r = i >> 6, d = i & 63;
            Xt[d * 34 + r] = x[(size_t)rowid_l[r] * 64 + d];
        }
        __syncthreads();

        // exact ||x||^2, numpy 8-acc pairwise
        if (tid < 32) {
            float rr[8];
#pragma unroll
            for (int j = 0; j < 8; ++j) { float v = Xt[j * 34 + tid]; rr[j] = v * v; }
#pragma unroll
            for (int i = 8; i < 64; i += 8)
#pragma unroll
                for (int j = 0; j < 8; ++j) { float v = Xt[(i + j) * 34 + tid]; rr[j] = rr[j] + v * v; }
            sx_l[tid] = ((rr[0] + rr[1]) + (rr[2] + rr[3])) + ((rr[4] + rr[5]) + (rr[6] + rr[7]));
        }
        __syncthreads();

        float b1[2]; int bi[2];
#pragma unroll
        for (int m = 0; m < 2; ++m) { b1[m] = 3.4e38f; bi[m] = 0; }

        for (int ch = 0; ch < 8; ++ch) {
            if (ch > 0) __syncthreads();
#pragma unroll
            for (int k = 0; k < 4; ++k) {
                int i = tid + k * 256;        // 0..1023 float4-units
                int c = i >> 4, c4 = i & 15;
                float4 v = *reinterpret_cast<const float4*>(&emb[(size_t)(ch * 64 + c) * 64 + c4 * 4]);
                Et[(c4 * 4 + 0) * 68 + c] = v.x;
                Et[(c4 * 4 + 1) * 68 + c] = v.y;
                Et[(c4 * 4 + 2) * 68 + c] = v.z;
                Et[(c4 * 4 + 3) * 68 + c] = v.w;
            }
            __syncthreads();

            float acc[2][4];
#pragma unroll
            for (int m = 0; m < 2; ++m)
#pragma unroll
                for (int nn = 0; nn < 4; ++nn) acc[m][nn] = 0.f;

            // sequential-k FMA chain, ascending d — bit-matches reference BLAS dot
#pragma unroll 8
            for (int d = 0; d < 64; ++d) {
                float2 a = *reinterpret_cast<const float2*>(&Xt[d * 34 + ty * 2]);
                float4 b = *reinterpret_cast<const float4*>(&Et[d * 68 + tx * 4]);
                float av[2] = {a.x, a.y};
                float bv[4] = {b.x, b.y, b.z, b.w};
#pragma unroll
                for (int m = 0; m < 2; ++m)
#pragma unroll
                    for (int nn = 0; nn < 4; ++nn)
                        acc[m][nn] = fmaf(av[m], bv[nn], acc[m][nn]);
            }

            const int cbase = ch * 64 + tx * 4;
            float4 bs4 = *reinterpret_cast<const float4*>(&bsq[cbase]);
            float bs[4] = {bs4.x, bs4.y, bs4.z, bs4.w};
#pragma unroll
            for (int m = 0; m < 2; ++m) {
                float sxm = sx_l[ty * 2 + m];
#pragma unroll
                for (int nn = 0; nn < 4; ++nn) {
                    float S  = sxm + bs[nn];
                    float dd = S - 2.0f * acc[m][nn];   // exact ref rounding
                    if (dd < b1[m]) { b1[m] = dd; bi[m] = cbase + nn; }
                }
            }
        }

        // reduce over 16 tx lanes; ties -> lowest index
#pragma unroll
        for (int off = 8; off >= 1; off >>= 1)
#pragma unroll
            for (int m = 0; m < 2; ++m) {
                float ov = __shfl_xor(b1[m], off, 64);
                int   oi = __shfl_xor(bi[m], off, 64);
                if (ov < b1[m] || (ov == b1[m] && oi < bi[m])) { b1[m] = ov; bi[m] = oi; }
            }

        if (tx == 0) {
#pragma unroll
            for (int m = 0; m < 2; ++m) {
                int rl = ty * 2 + m;
                if (rl < nrows) {
                    int row = rowid_l[rl];
                    int fi  = bi[m];
                    int old = (int)out[O_IDX + row];
                    if (fi != old) {
                        out[O_IDX + row] = (float)fi;
                        out[O_ENC + (size_t)row * KCODES + old] = 0.f;
                        out[O_ENC + (size_t)row * KCODES + fi]  = 1.f;
                        atomicAdd(&counts[old], -1);
                        atomicAdd(&counts[fi], 1);
                        double dl = 0.0;
                        for (int d = 0; d < 64; ++d) {
                            float xv   = Xt[d * 34 + rl];
                            float dn   = emb[(size_t)fi * 64 + d] - xv;
                            float dold = emb[(size_t)old * 64 + d] - xv;
                            out[O_Q + (size_t)row * 64 + d] = xv + dn;
                            dl += (double)dn * (double)dn - (double)dold * (double)dold;
                        }
                        atomicAdd(loss_acc, dl);
                    }
                }
            }
        }
        __syncthreads();   // protect Xt/rowid before next group
    }
}

// ---------------- K5 finalize: scalars ----------------
__global__ void vq_fin(const int* __restrict__ counts, const double* __restrict__ loss_acc,
                       float* __restrict__ out) {
    int t = threadIdx.x;     // 256
    double h = 0.0;
    for (int c = t; c < KCODES; c += 256) {
        double p = (double)counts[c] / (double)N_ROWS;
        h += p * log(p + 1e-10);
    }
#pragma unroll
    for (int off = 32; off >= 1; off >>= 1) h += __shfl_xor(h, off, 64);
    __shared__ double ws[4];
    if ((t & 63) == 0) ws[t >> 6] = h;
    __syncthreads();
    if (t == 0) {
        double H = ws[0] + ws[1] + ws[2] + ws[3];
        out[O_PERP] = (float)exp(-H);
        out[O_LOSS] = (float)(1.25 * (*loss_acc) / (double)(N_ROWS * DIM));
    }
}

extern "C" void kernel_launch(void* const* d_in, const int* in_sizes, int n_in,
                              void* d_out, int out_size, void* d_ws, size_t ws_size,
                              hipStream_t stream) {
    const float* x   = (const float*)d_in[0];
    const float* emb = (const float*)d_in[1];
    float* out = (float*)d_out;

    // ws: [0,2048) f32 bsq | [2048,4096) int counts | 4096 f64 loss |
    //     4112 int amb_count | [4160, 4160+4*AMB_CAP) int amb_rows
    float*  bsq       = (float*)d_ws;
    int*    counts    = (int*)((char*)d_ws + 2048);
    double* loss_acc  = (double*)((char*)d_ws + 4096);
    int*    amb_count = (int*)((char*)d_ws + 4112);
    int*    amb_rows  = (int*)((char*)d_ws + 4160);

    vq_prep<<<2, 256, 0, stream>>>(emb, bsq, counts, loss_acc, amb_count);
    vq_mfma<<<N_ROWS / 64, 256, 0, stream>>>(x, emb, bsq, counts, loss_acc, out,
                                             amb_count, amb_rows);
    vq_fixup<<<256, 256, 0, stream>>>(x, emb, bsq, counts, loss_acc, out,
                                      amb_count, amb_rows);
    vq_fin<<<1, 256, 0, stream>>>(counts, loss_acc, out);
}

// Round 6
// 192.859 us; speedup vs baseline: 1.2950x; 1.2950x over previous
//
#include <hip/hip_runtime.h>
#include <math.h>

#define N_ROWS 131072
#define DIM 64
#define KCODES 512

// float-element offsets into d_out (concatenated outputs, all read back as f32)
#define O_LOSS 0
#define O_Q    1ull
#define O_PERP 8388609ull
#define O_ENC  8388610ull
#define O_IDX  75497474ull

// flip-possible window: ref-side grid/rounding <= ~3.1e-5 per pair, our MFMA-path
// delta <= ~2.2e-5  => true bound ~5.3e-5. 1.5e-4 gives 2.8x safety.
// Expected ambiguous rows ~ 296/unit * 1.5e-4 * 131072 ~ 5.8K << cap.
#define AMB_WIN 1.5e-4f
#define AMB_CAP 32768

using sh8   = __attribute__((ext_vector_type(8))) short;
using f32x4 = __attribute__((ext_vector_type(4))) float;

// round-to-nearest-even bf16 of f32, returned as f32 bit pattern pre-shift
__device__ __forceinline__ unsigned bf16rne_bits(float x) {
    unsigned u = __float_as_uint(x);
    return u + 0x7fffu + ((u >> 16) & 1u);
}
// split v into bf16 hi + bf16(v - hi)  (hi-sub is exact; standard split)
__device__ __forceinline__ void bf16split(float v, unsigned short& h, unsigned short& s) {
    unsigned hb = bf16rne_bits(v);
    float hf = __uint_as_float(hb & 0xffff0000u);
    unsigned lb = bf16rne_bits(v - hf);
    h = (unsigned short)(hb >> 16);
    s = (unsigned short)(lb >> 16);
}

// ---------------- K1 prep: bsq (exact numpy pairwise), B-fragment tables, zeroing ----------------
// B-frag layout for mfma_16x16x32_bf16 (B[k][col], col=lane&15, k=(lane>>4)*8+j):
//   Bhi[((CT*2 + h)*64 + l)*8 + j] = bf16hi(emb[CT*16 + (l&15)][(l>>4)*8 + 32*h + j])
// so a wave's fragment load is 64 lanes x 16B contiguous = 1KB.
__global__ void vq_prep(const float* __restrict__ emb, float* __restrict__ bsq,
                        int* __restrict__ counts, double* __restrict__ loss_acc,
                        int* __restrict__ amb_count,
                        unsigned short* __restrict__ Bhi, unsigned short* __restrict__ Blo) {
#pragma clang fp contract(off)
    int t = blockIdx.x * 256 + threadIdx.x;     // grid 128 -> 0..32767
    if (t < KCODES * DIM) {
        int c = t >> 6, d = t & 63;
        unsigned short h, s;
        bf16split(emb[t], h, s);
        int CT = c >> 4, col = c & 15, hh = d >> 5, j = d & 7, lh = (d >> 3) & 3;
        int addr = ((CT * 2 + hh) * 64 + (lh * 16 + col)) * 8 + j;
        Bhi[addr] = h;
        Blo[addr] = s;
    }
    if (t < KCODES) {
        const float* e = emb + (size_t)t * DIM;
        float r[8];
#pragma unroll
        for (int j = 0; j < 8; ++j) { float v = e[j]; r[j] = v * v; }
#pragma unroll
        for (int i = 8; i < 64; i += 8)
#pragma unroll
            for (int j = 0; j < 8; ++j) { float v = e[i + j]; r[j] = r[j] + v * v; }
        bsq[t] = ((r[0] + r[1]) + (r[2] + r[3])) + ((r[4] + r[5]) + (r[6] + r[7]));
        counts[t] = 0;
    }
    if (t == 0) { *loss_acc = 0.0; *amb_count = 0; }
}

// ---------------- K2: MFMA distances (no LDS in loop) + provisional argmin + enc/Q/loss ----------------
__global__ __launch_bounds__(256) void vq_mfma(
    const float* __restrict__ x, const float* __restrict__ emb,
    const float* __restrict__ bsq,
    const unsigned short* __restrict__ Bhi, const unsigned short* __restrict__ Blo,
    int* __restrict__ counts, double* __restrict__ loss_acc, float* __restrict__ out,
    int* __restrict__ amb_count, int* __restrict__ amb_rows)
{
    __shared__ int    idx_l[64];
    __shared__ double wsum[4];

    const int tid  = threadIdx.x;
    const int l    = tid & 63;
    const int w    = tid >> 6;                 // wave 0..3
    const int row0 = blockIdx.x * 64;
    const int arow = row0 + w * 16 + (l & 15); // A row for this lane
    const int kb   = (l >> 4) * 8;             // lane k-offset

    // ---- A fragments: load 8-float k-slices from global, split in registers ----
    float4 a0 = *reinterpret_cast<const float4*>(&x[(size_t)arow * 64 + kb]);
    float4 a1 = *reinterpret_cast<const float4*>(&x[(size_t)arow * 64 + kb + 4]);
    float4 a2 = *reinterpret_cast<const float4*>(&x[(size_t)arow * 64 + kb + 32]);
    float4 a3 = *reinterpret_cast<const float4*>(&x[(size_t)arow * 64 + kb + 36]);
    unsigned short ah[16], al[16];
    {
        float av[16] = {a0.x,a0.y,a0.z,a0.w, a1.x,a1.y,a1.z,a1.w,
                        a2.x,a2.y,a2.z,a2.w, a3.x,a3.y,a3.z,a3.w};
#pragma unroll
        for (int i = 0; i < 16; ++i) bf16split(av[i], ah[i], al[i]);
    }
    sh8 ah0 = *reinterpret_cast<sh8*>(&ah[0]), ah1 = *reinterpret_cast<sh8*>(&ah[8]);
    sh8 al0 = *reinterpret_cast<sh8*>(&al[0]), al1 = *reinterpret_cast<sh8*>(&al[8]);

    float m1[4], m2[4];
    int   i1[4];
#pragma unroll
    for (int j = 0; j < 4; ++j) { m1[j] = 3.4e38f; m2[j] = 3.4e38f; i1[j] = 0; }

    const int col = l & 15;
#pragma unroll 4
    for (int CT = 0; CT < 32; ++CT) {
        sh8 bh0 = *reinterpret_cast<const sh8*>(&Bhi[(size_t)(CT * 2 + 0) * 512 + l * 8]);
        sh8 bh1 = *reinterpret_cast<const sh8*>(&Bhi[(size_t)(CT * 2 + 1) * 512 + l * 8]);
        sh8 bl0 = *reinterpret_cast<const sh8*>(&Blo[(size_t)(CT * 2 + 0) * 512 + l * 8]);
        sh8 bl1 = *reinterpret_cast<const sh8*>(&Blo[(size_t)(CT * 2 + 1) * 512 + l * 8]);
        f32x4 acc = {0.f, 0.f, 0.f, 0.f};
        acc = __builtin_amdgcn_mfma_f32_16x16x32_bf16(ah0, bh0, acc, 0, 0, 0);
        acc = __builtin_amdgcn_mfma_f32_16x16x32_bf16(ah1, bh1, acc, 0, 0, 0);
        acc = __builtin_amdgcn_mfma_f32_16x16x32_bf16(ah0, bl0, acc, 0, 0, 0);
        acc = __builtin_amdgcn_mfma_f32_16x16x32_bf16(ah1, bl1, acc, 0, 0, 0);
        acc = __builtin_amdgcn_mfma_f32_16x16x32_bf16(al0, bh0, acc, 0, 0, 0);
        acc = __builtin_amdgcn_mfma_f32_16x16x32_bf16(al1, bh1, acc, 0, 0, 0);

        int code = CT * 16 + col;
        float bs = bsq[code];
#pragma unroll
        for (int j = 0; j < 4; ++j) {
            float tt = bs - 2.0f * acc[j];     // ||x||^2 dropped: uniform per-row shift
            if (tt < m1[j]) { m2[j] = m1[j]; m1[j] = tt; i1[j] = code; }
            else if (tt < m2[j]) { m2[j] = tt; }
        }
    }

    // ---- reduce (min, argmin, 2nd-min) across the 16 lanes sharing (l>>4) ----
#pragma unroll
    for (int off = 8; off >= 1; off >>= 1)
#pragma unroll
        for (int j = 0; j < 4; ++j) {
            float ov1 = __shfl_xor(m1[j], off, 64);
            int   oi1 = __shfl_xor(i1[j], off, 64);
            float ov2 = __shfl_xor(m2[j], off, 64);
            float hi  = fmaxf(m1[j], ov1);
            m2[j] = fminf(fminf(m2[j], ov2), hi);
            if (ov1 < m1[j] || (ov1 == m1[j] && oi1 < i1[j])) { m1[j] = ov1; i1[j] = oi1; }
        }

    if ((l & 15) == 0) {
#pragma unroll
        for (int j = 0; j < 4; ++j) {
            int r_loc = w * 16 + ((l >> 4) << 2) + j;   // D row = (lane>>4)*4 + reg
            idx_l[r_loc] = i1[j];
            out[O_IDX + row0 + r_loc] = (float)i1[j];
            atomicAdd(&counts[i1[j]], 1);
            if (m2[j] - m1[j] <= AMB_WIN) {
                int slot = atomicAdd(amb_count, 1);
                if (slot < AMB_CAP) amb_rows[slot] = row0 + r_loc;
            }
        }
    }
    __syncthreads();

    // ---- quantized_st + loss partial (x re-read is L2-hot) ----
    double lsum = 0.0;
#pragma unroll 4
    for (int k = 0; k < 16; ++k) {
        int i = tid + k * 256;               // 0..4095
        int r = i >> 6, d = i & 63;
        int id = idx_l[r];
        float xv = x[(size_t)(row0 + r) * 64 + d];
        float ev = emb[(size_t)id * 64 + d];
        float diff = ev - xv;
        out[O_Q + (size_t)(row0 + r) * 64 + d] = xv + diff;
        lsum += (double)diff * (double)diff;
    }

    // ---- one-hot encodings (64 rows x 512) as float2 (O_ENC is 8B- not 16B-aligned) ----
    float2* enc2 = reinterpret_cast<float2*>(out + O_ENC + (size_t)row0 * KCODES);
#pragma unroll 4
    for (int k = 0; k < 64; ++k) {
        int i = tid + k * 256;               // 0..16383 float2s
        int r = i >> 8;
        int c = (i & 255) * 2;
        int id = idx_l[r];
        float2 v;
        v.x = (c     == id) ? 1.f : 0.f;
        v.y = (c + 1 == id) ? 1.f : 0.f;
        enc2[i] = v;
    }

#pragma unroll
    for (int off = 32; off >= 1; off >>= 1) lsum += __shfl_xor(lsum, off, 64);
    if ((tid & 63) == 0) wsum[tid >> 6] = lsum;
    __syncthreads();
    if (tid == 0) atomicAdd(loss_acc, wsum[0] + wsum[1] + wsum[2] + wsum[3]);
}

// ---------------- K3: bit-exact np-replica recompute for ambiguous rows ----------------
__global__ __launch_bounds__(256, 2) void vq_fixup(
    const float* __restrict__ x, const float* __restrict__ emb,
    const float* __restrict__ bsq, int* __restrict__ counts,
    double* __restrict__ loss_acc, float* __restrict__ out,
    const int* __restrict__ amb_count, const int* __restrict__ amb_rows)
{
#pragma clang fp contract(off)
    __shared__ float Xt[64 * 34];     // Xt[d*34 + r], 32 rows
    __shared__ float Et[64 * 68];     // Et[d*68 + c], 64 codes/chunk
    __shared__ float sx_l[32];
    __shared__ int   rowid_l[32];

    const int tid = threadIdx.x;
    const int tx  = tid & 15;         // 4 codes each
    const int ty  = tid >> 4;         // 2 rows each
    int n = *amb_count; if (n > AMB_CAP) n = AMB_CAP;

    for (int base = blockIdx.x * 32; base < n; base += gridDim.x * 32) {
        const int nrows = min(32, n - base);
        if (tid < 32) {
            int e = base + tid;
            rowid_l[tid] = amb_rows[e < n ? e : (n - 1)];
        }
        __syncthreads();

        // stage X rows transposed
#pragma unroll
        for (int k = 0; k < 8; ++k) {
            int i = tid + k * 256;    // 0..2047
            int r = i >> 6, d = i & 63;
            Xt[d * 34 + r] = x[(size_t)rowid_l[r] * 64 + d];
        }
        __syncthreads();

        // exact ||x||^2, numpy 8-acc pairwise
        if (tid < 32) {
            float rr[8];
#pragma unroll
            for (int j = 0; j < 8; ++j) { float v = Xt[j * 34 + tid]; rr[j] = v * v; }
#pragma unroll
            for (int i = 8; i < 64; i += 8)
#pragma unroll
                for (int j = 0; j < 8; ++j) { float v = Xt[(i + j) * 34 + tid]; rr[j] = rr[j] + v * v; }
            sx_l[tid] = ((rr[0] + rr[1]) + (rr[2] + rr[3])) + ((rr[4] + rr[5]) + (rr[6] + rr[7]));
        }
        __syncthreads();

        float b1[2]; int bi[2];
#pragma unroll
        for (int m = 0; m < 2; ++m) { b1[m] = 3.4e38f; bi[m] = 0; }

        for (int ch = 0; ch < 8; ++ch) {
            if (ch > 0) __syncthreads();
#pragma unroll
            for (int k = 0; k < 4; ++k) {
                int i = tid + k * 256;        // 0..1023 float4-units
                int c = i >> 4, c4 = i & 15;
                float4 v = *reinterpret_cast<const float4*>(&emb[(size_t)(ch * 64 + c) * 64 + c4 * 4]);
                Et[(c4 * 4 + 0) * 68 + c] = v.x;
                Et[(c4 * 4 + 1) * 68 + c] = v.y;
                Et[(c4 * 4 + 2) * 68 + c] = v.z;
                Et[(c4 * 4 + 3) * 68 + c] = v.w;
            }
            __syncthreads();

            float acc[2][4];
#pragma unroll
            for (int m = 0; m < 2; ++m)
#pragma unroll
                for (int nn = 0; nn < 4; ++nn) acc[m][nn] = 0.f;

            // sequential-k FMA chain, ascending d — bit-matches reference BLAS dot
#pragma unroll 8
            for (int d = 0; d < 64; ++d) {
                float2 a = *reinterpret_cast<const float2*>(&Xt[d * 34 + ty * 2]);
                float4 b = *reinterpret_cast<const float4*>(&Et[d * 68 + tx * 4]);
                float av[2] = {a.x, a.y};
                float bv[4] = {b.x, b.y, b.z, b.w};
#pragma unroll
                for (int m = 0; m < 2; ++m)
#pragma unroll
                    for (int nn = 0; nn < 4; ++nn)
                        acc[m][nn] = fmaf(av[m], bv[nn], acc[m][nn]);
            }

            const int cbase = ch * 64 + tx * 4;
            float4 bs4 = *reinterpret_cast<const float4*>(&bsq[cbase]);
            float bs[4] = {bs4.x, bs4.y, bs4.z, bs4.w};
#pragma unroll
            for (int m = 0; m < 2; ++m) {
                float sxm = sx_l[ty * 2 + m];
#pragma unroll
                for (int nn = 0; nn < 4; ++nn) {
                    float S  = sxm + bs[nn];
                    float dd = S - 2.0f * acc[m][nn];   // exact ref rounding
                    if (dd < b1[m]) { b1[m] = dd; bi[m] = cbase + nn; }
                }
            }
        }

        // reduce over 16 tx lanes; ties -> lowest index
#pragma unroll
        for (int off = 8; off >= 1; off >>= 1)
#pragma unroll
            for (int m = 0; m < 2; ++m) {
                float ov = __shfl_xor(b1[m], off, 64);
                int   oi = __shfl_xor(bi[m], off, 64);
                if (ov < b1[m] || (ov == b1[m] && oi < bi[m])) { b1[m] = ov; bi[m] = oi; }
            }

        if (tx == 0) {
#pragma unroll
            for (int m = 0; m < 2; ++m) {
                int rl = ty * 2 + m;
                if (rl < nrows) {
                    int row = rowid_l[rl];
                    int fi  = bi[m];
                    int old = (int)out[O_IDX + row];
                    if (fi != old) {
                        out[O_IDX + row] = (float)fi;
                        out[O_ENC + (size_t)row * KCODES + old] = 0.f;
                        out[O_ENC + (size_t)row * KCODES + fi]  = 1.f;
                        atomicAdd(&counts[old], -1);
                        atomicAdd(&counts[fi], 1);
                        double dl = 0.0;
                        for (int d = 0; d < 64; ++d) {
                            float xv   = Xt[d * 34 + rl];
                            float dn   = emb[(size_t)fi * 64 + d] - xv;
                            float dold = emb[(size_t)old * 64 + d] - xv;
                            out[O_Q + (size_t)row * 64 + d] = xv + dn;
                            dl += (double)dn * (double)dn - (double)dold * (double)dold;
                        }
                        atomicAdd(loss_acc, dl);
                    }
                }
            }
        }
        __syncthreads();   // protect Xt/rowid before next group
    }
}

// ---------------- K4 finalize: scalars ----------------
__global__ void vq_fin(const int* __restrict__ counts, const double* __restrict__ loss_acc,
                       float* __restrict__ out) {
    int t = threadIdx.x;     // 256
    double h = 0.0;
    for (int c = t; c < KCODES; c += 256) {
        double p = (double)counts[c] / (double)N_ROWS;
        h += p * log(p + 1e-10);
    }
#pragma unroll
    for (int off = 32; off >= 1; off >>= 1) h += __shfl_xor(h, off, 64);
    __shared__ double ws[4];
    if ((t & 63) == 0) ws[t >> 6] = h;
    __syncthreads();
    if (t == 0) {
        double H = ws[0] + ws[1] + ws[2] + ws[3];
        out[O_PERP] = (float)exp(-H);
        out[O_LOSS] = (float)(1.25 * (*loss_acc) / (double)(N_ROWS * DIM));
    }
}

extern "C" void kernel_launch(void* const* d_in, const int* in_sizes, int n_in,
                              void* d_out, int out_size, void* d_ws, size_t ws_size,
                              hipStream_t stream) {
    const float* x   = (const float*)d_in[0];
    const float* emb = (const float*)d_in[1];
    float* out = (float*)d_out;

    // ws: [0,2048) f32 bsq | [2048,4096) int counts | 4096 f64 loss | 4112 amb_count |
    //     [4160, 4160+4*AMB_CAP) amb_rows | 139264 Bhi (64KB) | 212992 Blo (64KB)
    float*          bsq       = (float*)d_ws;
    int*            counts    = (int*)((char*)d_ws + 2048);
    double*         loss_acc  = (double*)((char*)d_ws + 4096);
    int*            amb_count = (int*)((char*)d_ws + 4112);
    int*            amb_rows  = (int*)((char*)d_ws + 4160);
    unsigned short* Bhi       = (unsigned short*)((char*)d_ws + 139264);
    unsigned short* Blo       = (unsigned short*)((char*)d_ws + 212992);

    vq_prep<<<128, 256, 0, stream>>>(emb, bsq, counts, loss_acc, amb_count, Bhi, Blo);
    vq_mfma<<<N_ROWS / 64, 256, 0, stream>>>(x, emb, bsq, Bhi, Blo, counts, loss_acc, out,
                                             amb_count, amb_rows);
    vq_fixup<<<1024, 256, 0, stream>>>(x, emb, bsq, counts, loss_acc, out,
                                       amb_count, amb_rows);
    vq_fin<<<1, 256, 0, stream>>>(counts, loss_acc, out);
}